// Round 2
// baseline (811.810 us; speedup 1.0000x reference)
//
#include <hip/hip_runtime.h>

// VectorBasis: fused edge-expansion + scatter + per-atom contraction.
// R2: privatize the accumulator per-XCD (8 copies in d_ws) and use
// WORKGROUP-scope atomics so the fadd executes in the XCD-local L2 instead of
// writing 32B through the fabric per op (R1: WRITE_SIZE=450MB = 14.4M x 32B).
// Blocks on different XCDs never share a buffer (indexed by HW_REG_XCC_ID),
// so L2-local atomicity is sufficient. Kernel 2 reduces the 8 partials.

constexpr int NSP  = 4;   // species
constexpr int NRAD = 8;   // radial functions
constexpr int NPS  = 4;   // pseudo species
constexpr int DDIM = NRAD * NPS;  // 32
constexpr int NXCD = 8;

__device__ __forceinline__ unsigned xcc_id() {
    unsigned x;
    asm volatile("s_getreg_b32 %0, hwreg(20, 0, 32)" : "=s"(x));  // HW_REG_XCC_ID
    return x & 7u;
}

template <bool PRIV>
__global__ __launch_bounds__(256) void vb_edge_kernel(
    const float* __restrict__ vecs,       // (E,3)
    const int*   __restrict__ centers,    // (E,)
    const int*   __restrict__ neighbors,  // (E,)
    const int*   __restrict__ species,    // (A,)
    const float* __restrict__ W_alch,     // (NSP, NPS)
    const float* __restrict__ cemb,       // (NSP, D)
    const float* __restrict__ Wc,         // (3, D)
    float*       __restrict__ dst,        // PRIV: (8, A, 9) partials; else (A,3,3)
    int E, int out_elems)
{
    // M[o][d][s] = cemb[s][d] * Wc[o][d]; species innermost -> adjacent banks.
    __shared__ float sM[3][DDIM][NSP];    // 384 floats
    __shared__ float sAl[NPS][NSP];       // 16 floats, transposed W_alch

    for (int i = threadIdx.x; i < 3 * DDIM * NSP; i += blockDim.x) {
        int s  = i & 3;
        int dd = (i >> 2) & 31;
        int o  = i >> 7;
        sM[o][dd][s] = cemb[s * DDIM + dd] * Wc[o * DDIM + dd];
    }
    if (threadIdx.x < NPS * NSP) {
        int q = threadIdx.x >> 2;
        int s = threadIdx.x & 3;
        sAl[q][s] = W_alch[s * NPS + q];
    }
    __syncthreads();

    float* mybuf = dst;
    if (PRIV) mybuf = dst + (size_t)xcc_id() * out_elems;

    int e = blockIdx.x * blockDim.x + threadIdx.x;
    if (e >= E) return;

    float vx = vecs[3 * e + 0];
    float vy = vecs[3 * e + 1];
    float vz = vecs[3 * e + 2];
    int c  = centers[e];
    int nb = neighbors[e];
    int sn = species[nb];
    int sc = species[c];

    float d2    = vx * vx + vy * vy + vz * vz + 1e-12f;
    float d     = sqrtf(d2);
    float inv_d = 1.0f / d;

    const float PI = 3.14159265358979323846f;
    const float RCUT = 5.0f, INNER = 4.5f, INVW = 2.0f;  // 1/width
    float taper = 0.5f * (cosf(PI * (d - INNER) * INVW) + 1.0f);
    float fc = (d < INNER) ? 1.0f : ((d < RCUT) ? taper : 0.0f);

    // R[n] = sin((n+1)*theta)/d via Chebyshev recurrence.
    float theta = (PI / RCUT) * d;
    float s1 = sinf(theta);
    float c1 = cosf(theta);
    float two_c = 2.0f * c1;
    float R[NRAD];
    R[0] = s1 * inv_d;
    float sm2 = 0.0f, sm1 = s1;
    #pragma unroll
    for (int n = 1; n < NRAD; n++) {
        float s = two_c * sm1 - sm2;
        sm2 = sm1; sm1 = s;
        R[n] = s * inv_d;
    }

    float a0 = sAl[0][sn], a1 = sAl[1][sn], a2 = sAl[2][sn], a3 = sAl[3][sn];

    float tacc[3];
    #pragma unroll
    for (int o = 0; o < 3; o++) {
        float acc = 0.0f;
        #pragma unroll
        for (int n = 0; n < NRAD; n++) {
            int dbase = n * NPS;
            float w = sM[o][dbase + 0][sc] * a0
                    + sM[o][dbase + 1][sc] * a1
                    + sM[o][dbase + 2][sc] * a2
                    + sM[o][dbase + 3][sc] * a3;
            acc += R[n] * w;
        }
        tacc[o] = acc;
    }

    // Y order (-1,0,1) -> (y,z,x)/d
    float g[3];
    g[0] = fc * vy * inv_d;
    g[1] = fc * vz * inv_d;
    g[2] = fc * vx * inv_d;

    float* op = mybuf + (size_t)c * 9;
    #pragma unroll
    for (int m = 0; m < 3; m++) {
        #pragma unroll
        for (int o = 0; o < 3; o++) {
            float v = g[m] * tacc[o];
            if (PRIV) {
                // Executes in XCD-local L2 (no device-scope write-through).
                __hip_atomic_fetch_add(op + m * 3 + o, v,
                                       __ATOMIC_RELAXED, __HIP_MEMORY_SCOPE_WORKGROUP);
            } else {
                atomicAdd(op + m * 3 + o, v);
            }
        }
    }
}

__global__ __launch_bounds__(256) void vb_reduce_kernel(
    const float* __restrict__ part,   // (8, out_elems)
    float*       __restrict__ out,    // (out_elems)
    int out_elems)
{
    int i = blockIdx.x * blockDim.x + threadIdx.x;
    if (i >= out_elems) return;
    float s = 0.0f;
    #pragma unroll
    for (int x = 0; x < NXCD; x++)
        s += part[(size_t)x * out_elems + i];
    out[i] = s;
}

extern "C" void kernel_launch(void* const* d_in, const int* in_sizes, int n_in,
                              void* d_out, int out_size, void* d_ws, size_t ws_size,
                              hipStream_t stream) {
    const float* vecs      = (const float*)d_in[0];
    const int*   centers   = (const int*)d_in[1];
    const int*   neighbors = (const int*)d_in[2];
    const int*   species   = (const int*)d_in[3];
    const float* W_alch    = (const float*)d_in[6];
    const float* cemb      = (const float*)d_in[7];
    const float* Wc        = (const float*)d_in[8];
    float*       out       = (float*)d_out;

    int E = in_sizes[1];
    size_t need = (size_t)NXCD * out_size * sizeof(float);

    int block = 256;
    int grid  = (E + block - 1) / block;

    if (ws_size >= need) {
        float* part = (float*)d_ws;
        hipMemsetAsync(d_ws, 0, need, stream);
        vb_edge_kernel<true><<<grid, block, 0, stream>>>(
            vecs, centers, neighbors, species, W_alch, cemb, Wc, part, E, out_size);
        int rgrid = (out_size + block - 1) / block;
        vb_reduce_kernel<<<rgrid, block, 0, stream>>>(part, out, out_size);
    } else {
        hipMemsetAsync(d_out, 0, (size_t)out_size * sizeof(float), stream);
        vb_edge_kernel<false><<<grid, block, 0, stream>>>(
            vecs, centers, neighbors, species, W_alch, cemb, Wc, out, E, out_size);
    }
}

// Round 3
// 236.967 us; speedup vs baseline: 3.4258x; 3.4258x over previous
//
#include <hip/hip_runtime.h>

// VectorBasis R3: two-phase binned reduction.
// R1/R2 showed the wall is global f32 atomic op rate (~20 G/s; WRITE_SIZE =
// ops x 32B write-through). Fix: phase 1 computes per-edge (c, g[3], t[3]) and
// appends a 32B record to a per-bin bucket (bin = center>>9), reserving slots
// with ONE global atomic per (block,bin) via an LDS histogram (77K global
// atomics instead of 14.4M). Phase 2: one block per bin accumulates into an
// LDS accumulator (512 atoms x 9 f32) with LDS atomics, then coalesced += to
// d_out. Overflow slots (CAP exceeded; ~never) use direct global atomics.

constexpr int NSP  = 4;   // species
constexpr int NRAD = 8;   // radial functions
constexpr int NPS  = 4;   // pseudo species
constexpr int DDIM = NRAD * NPS;  // 32

constexpr int APB     = 512;   // atoms per bin
constexpr int APB_SH  = 9;
constexpr int MAXBIN  = 256;
constexpr int PH1_BLK = 512;
constexpr int PH1_U   = 8;     // edges per thread in phase 1

__device__ __forceinline__ void edge_math(
    float vx, float vy, float vz, int sc, int sn,
    const float (*sM)[DDIM][NSP], const float (*sAl)[NSP],
    float g[3], float t[3])
{
    float d2    = vx * vx + vy * vy + vz * vz + 1e-12f;
    float d     = sqrtf(d2);
    float inv_d = 1.0f / d;

    const float PI = 3.14159265358979323846f;
    const float RCUT = 5.0f, INNER = 4.5f, INVW = 2.0f;  // 1/width
    float taper = 0.5f * (cosf(PI * (d - INNER) * INVW) + 1.0f);
    float fc = (d < INNER) ? 1.0f : ((d < RCUT) ? taper : 0.0f);

    // R[n] = sin((n+1)*theta)/d via Chebyshev recurrence.
    float theta = (PI / RCUT) * d;
    float s1 = sinf(theta);
    float c1 = cosf(theta);
    float two_c = 2.0f * c1;
    float R[NRAD];
    R[0] = s1 * inv_d;
    float sm2 = 0.0f, sm1 = s1;
    #pragma unroll
    for (int n = 1; n < NRAD; n++) {
        float s = two_c * sm1 - sm2;
        sm2 = sm1; sm1 = s;
        R[n] = s * inv_d;
    }

    float a0 = sAl[0][sn], a1 = sAl[1][sn], a2 = sAl[2][sn], a3 = sAl[3][sn];

    #pragma unroll
    for (int o = 0; o < 3; o++) {
        float acc = 0.0f;
        #pragma unroll
        for (int n = 0; n < NRAD; n++) {
            int db = n * NPS;
            acc += R[n] * (sM[o][db + 0][sc] * a0
                         + sM[o][db + 1][sc] * a1
                         + sM[o][db + 2][sc] * a2
                         + sM[o][db + 3][sc] * a3);
        }
        t[o] = acc;
    }
    // Y order (-1,0,1) -> (y,z,x)/d
    g[0] = fc * vy * inv_d;
    g[1] = fc * vz * inv_d;
    g[2] = fc * vx * inv_d;
}

__global__ __launch_bounds__(PH1_BLK) void vb_phase1(
    const float* __restrict__ vecs,
    const int*   __restrict__ centers,
    const int*   __restrict__ neighbors,
    const int*   __restrict__ species,
    const float* __restrict__ W_alch,
    const float* __restrict__ cemb,
    const float* __restrict__ Wc,
    int*         __restrict__ gcursor,   // (nbin)
    float4*      __restrict__ payload,   // (nbin, cap, 2) float4
    float*       __restrict__ out,       // (A,9) overflow fallback target
    int E, int nbin, int cap)
{
    __shared__ float sM[3][DDIM][NSP];   // M[o][d][s] = cemb[s][d]*Wc[o][d]
    __shared__ float sAl[NPS][NSP];      // transposed W_alch
    __shared__ int   lcount[MAXBIN], lbase[MAXBIN], lofs[MAXBIN];

    for (int i = threadIdx.x; i < 3 * DDIM * NSP; i += blockDim.x) {
        int s  = i & 3;
        int dd = (i >> 2) & 31;
        int o  = i >> 7;
        sM[o][dd][s] = cemb[s * DDIM + dd] * Wc[o * DDIM + dd];
    }
    if (threadIdx.x < NPS * NSP) {
        int q = threadIdx.x >> 2;
        int s = threadIdx.x & 3;
        sAl[q][s] = W_alch[s * NPS + q];
    }
    for (int i = threadIdx.x; i < nbin; i += blockDim.x) { lcount[i] = 0; lofs[i] = 0; }
    __syncthreads();

    int base = blockIdx.x * (PH1_BLK * PH1_U) + threadIdx.x;
    int   ce[PH1_U];
    float gg[PH1_U][3], tt[PH1_U][3];

    #pragma unroll
    for (int u = 0; u < PH1_U; u++) {
        int e = base + u * PH1_BLK;
        ce[u] = -1;
        if (e < E) {
            float vx = vecs[3 * e + 0];
            float vy = vecs[3 * e + 1];
            float vz = vecs[3 * e + 2];
            int c  = centers[e];
            int nb = neighbors[e];
            edge_math(vx, vy, vz, species[c], species[nb], sM, sAl, gg[u], tt[u]);
            ce[u] = c;
            atomicAdd(&lcount[c >> APB_SH], 1);
        }
    }
    __syncthreads();

    // One global atomic per (block, non-empty bin) to reserve slots.
    for (int i = threadIdx.x; i < nbin; i += blockDim.x) {
        int n = lcount[i];
        lbase[i] = n ? atomicAdd(&gcursor[i], n) : 0;
    }
    __syncthreads();

    #pragma unroll
    for (int u = 0; u < PH1_U; u++) {
        if (ce[u] >= 0) {
            int bin = ce[u] >> APB_SH;
            int s = lbase[bin] + atomicAdd(&lofs[bin], 1);
            if (s < cap) {
                size_t idx = ((size_t)bin * cap + s) * 2;
                payload[idx]     = make_float4(gg[u][0], gg[u][1], gg[u][2],
                                               __int_as_float(ce[u]));
                payload[idx + 1] = make_float4(tt[u][0], tt[u][1], tt[u][2], 0.0f);
            } else {
                // overflow (statistically ~never): direct global atomics
                float* op = out + (size_t)ce[u] * 9;
                #pragma unroll
                for (int m = 0; m < 3; m++)
                    #pragma unroll
                    for (int o = 0; o < 3; o++)
                        atomicAdd(op + m * 3 + o, gg[u][m] * tt[u][o]);
            }
        }
    }
}

__global__ __launch_bounds__(256) void vb_phase2(
    const int*    __restrict__ gcursor,
    const float4* __restrict__ payload,
    float*        __restrict__ out,
    int out_elems, int cap)
{
    __shared__ float acc[APB * 9];   // 18 KB
    int b = blockIdx.x;
    for (int i = threadIdx.x; i < APB * 9; i += blockDim.x) acc[i] = 0.0f;
    __syncthreads();

    int count = min(gcursor[b], cap);
    size_t pbase = (size_t)b * cap * 2;
    for (int i = threadIdx.x; i < count; i += blockDim.x) {
        float4 p0 = payload[pbase + 2 * (size_t)i];
        float4 p1 = payload[pbase + 2 * (size_t)i + 1];
        int c  = __float_as_int(p0.w);
        int cl = (c & (APB - 1)) * 9;
        float g0 = p0.x, g1 = p0.y, g2 = p0.z;
        float t0 = p1.x, t1 = p1.y, t2 = p1.z;
        atomicAdd(&acc[cl + 0], g0 * t0);
        atomicAdd(&acc[cl + 1], g0 * t1);
        atomicAdd(&acc[cl + 2], g0 * t2);
        atomicAdd(&acc[cl + 3], g1 * t0);
        atomicAdd(&acc[cl + 4], g1 * t1);
        atomicAdd(&acc[cl + 5], g1 * t2);
        atomicAdd(&acc[cl + 6], g2 * t0);
        atomicAdd(&acc[cl + 7], g2 * t1);
        atomicAdd(&acc[cl + 8], g2 * t2);
    }
    __syncthreads();

    size_t gb = (size_t)b * APB * 9;
    for (int i = threadIdx.x; i < APB * 9; i += blockDim.x) {
        size_t gi = gb + i;
        if (gi < (size_t)out_elems) out[gi] += acc[i];
    }
}

// Fallback (R1): direct per-edge global atomics — used only if d_ws too small.
__global__ __launch_bounds__(256) void vb_edge_kernel(
    const float* __restrict__ vecs,
    const int*   __restrict__ centers,
    const int*   __restrict__ neighbors,
    const int*   __restrict__ species,
    const float* __restrict__ W_alch,
    const float* __restrict__ cemb,
    const float* __restrict__ Wc,
    float*       __restrict__ out,
    int E)
{
    __shared__ float sM[3][DDIM][NSP];
    __shared__ float sAl[NPS][NSP];

    for (int i = threadIdx.x; i < 3 * DDIM * NSP; i += blockDim.x) {
        int s  = i & 3;
        int dd = (i >> 2) & 31;
        int o  = i >> 7;
        sM[o][dd][s] = cemb[s * DDIM + dd] * Wc[o * DDIM + dd];
    }
    if (threadIdx.x < NPS * NSP) {
        int q = threadIdx.x >> 2;
        int s = threadIdx.x & 3;
        sAl[q][s] = W_alch[s * NPS + q];
    }
    __syncthreads();

    int e = blockIdx.x * blockDim.x + threadIdx.x;
    if (e >= E) return;

    float vx = vecs[3 * e + 0];
    float vy = vecs[3 * e + 1];
    float vz = vecs[3 * e + 2];
    int c  = centers[e];
    int nb = neighbors[e];
    float g[3], t[3];
    edge_math(vx, vy, vz, species[c], species[nb], sM, sAl, g, t);

    float* op = out + (size_t)c * 9;
    #pragma unroll
    for (int m = 0; m < 3; m++)
        #pragma unroll
        for (int o = 0; o < 3; o++)
            atomicAdd(op + m * 3 + o, g[m] * t[o]);
}

extern "C" void kernel_launch(void* const* d_in, const int* in_sizes, int n_in,
                              void* d_out, int out_size, void* d_ws, size_t ws_size,
                              hipStream_t stream) {
    const float* vecs      = (const float*)d_in[0];
    const int*   centers   = (const int*)d_in[1];
    const int*   neighbors = (const int*)d_in[2];
    const int*   species   = (const int*)d_in[3];
    const float* W_alch    = (const float*)d_in[6];
    const float* cemb      = (const float*)d_in[7];
    const float* Wc        = (const float*)d_in[8];
    float*       out       = (float*)d_out;

    int E = in_sizes[1];
    int A = in_sizes[3];
    int nbin = (A + APB - 1) >> APB_SH;

    // Workspace layout: [gcursor: 1024 B][payload: nbin*cap*32 B]
    long cap = 0;
    if (ws_size > 1024) {
        cap = (long)((ws_size - 1024) / 32) / nbin;
        cap &= ~255L;
        if (cap > 16384) cap = 16384;
    }
    long mean = (long)E / nbin + 1;

    hipMemsetAsync(d_out, 0, (size_t)out_size * sizeof(float), stream);

    if (nbin <= MAXBIN && cap >= mean + mean / 16) {
        int*    gcursor = (int*)d_ws;
        float4* payload = (float4*)((char*)d_ws + 1024);
        hipMemsetAsync(d_ws, 0, 1024, stream);

        int g1 = (E + PH1_BLK * PH1_U - 1) / (PH1_BLK * PH1_U);
        vb_phase1<<<g1, PH1_BLK, 0, stream>>>(vecs, centers, neighbors, species,
                                              W_alch, cemb, Wc,
                                              gcursor, payload, out,
                                              E, nbin, (int)cap);
        vb_phase2<<<nbin, 256, 0, stream>>>(gcursor, payload, out,
                                            out_size, (int)cap);
    } else {
        int block = 256;
        int grid  = (E + block - 1) / block;
        vb_edge_kernel<<<grid, block, 0, stream>>>(vecs, centers, neighbors, species,
                                                   W_alch, cemb, Wc, out, E);
    }
}

// Round 4
// 217.531 us; speedup vs baseline: 3.7319x; 1.0893x over previous
//
#include <hip/hip_runtime.h>
#include <hip/hip_fp16.h>

// VectorBasis R4. Two-phase binned reduction (R3) with:
//  - pair-table W2[o][n][(sc,sn)] in LDS: 24 ds_read/edge instead of 100
//  - 16B f16 payload records (halves payload traffic)
//  - phase2 split 4-ways per bin into 4 partial outputs (grid 196->784,
//    fixes 8.5% occupancy), summed by a tiny reduce kernel.

constexpr int NSP  = 4;
constexpr int NRAD = 8;
constexpr int NPS  = 4;
constexpr int DDIM = NRAD * NPS;   // 32

constexpr int APB      = 512;      // atoms per bin
constexpr int APB_SH   = 9;
constexpr int NBIN_MAX = 256;
constexpr int SPLIT    = 4;        // phase2 sub-blocks per bin
constexpr int PH1_BLK  = 512;
constexpr int PH1_U    = 8;        // edges per thread, phase 1

__device__ __forceinline__ unsigned pack2(float a, float b) {
    union { __half2 h; unsigned u; } cv;
    cv.h = __floats2half2_rn(a, b);
    return cv.u;
}
__device__ __forceinline__ float2 unpack2(unsigned u) {
    union { unsigned u; __half2 h; } cv;
    cv.u = u;
    return __half22float2(cv.h);
}

// Build W2[(o*8+n)*16 + (sc*4+sn)] = sum_q cemb[sc][n*4+q]*Wc[o][n*4+q]*alch[sn][q]
__device__ __forceinline__ void build_w2(
    float* sW2, const float* cemb, const float* Wc, const float* W_alch,
    int tid, int nthreads)
{
    for (int i = tid; i < 3 * NRAD * 16; i += nthreads) {
        int p  = i & 15;
        int n  = (i >> 4) & 7;
        int o  = i >> 7;
        int sc = p >> 2, sn = p & 3;
        float w = 0.0f;
        #pragma unroll
        for (int q = 0; q < NPS; q++)
            w += cemb[sc * DDIM + n * NPS + q] * Wc[o * DDIM + n * NPS + q]
               * W_alch[sn * NPS + q];
        sW2[i] = w;
    }
}

// Per-edge math: outputs g[3] (fc*Y) and t[3] (radial x pair-weight dot).
__device__ __forceinline__ bool edge_math(
    float vx, float vy, float vz, int pair, const float* sW2,
    float g[3], float t[3])
{
    float d2    = vx * vx + vy * vy + vz * vz + 1e-12f;
    float d     = sqrtf(d2);
    float inv_d = 1.0f / d;

    const float PI = 3.14159265358979323846f;
    const float RCUT = 5.0f, INNER = 4.5f, INVW = 2.0f;
    if (d >= RCUT) return false;           // fc == 0, contributes nothing
    float taper = 0.5f * (cosf(PI * (d - INNER) * INVW) + 1.0f);
    float fc = (d < INNER) ? 1.0f : taper;

    float theta = (PI / RCUT) * d;
    float s1 = sinf(theta);
    float c1 = cosf(theta);
    float two_c = 2.0f * c1;
    float R[NRAD];
    R[0] = s1 * inv_d;
    float sm2 = 0.0f, sm1 = s1;
    #pragma unroll
    for (int n = 1; n < NRAD; n++) {
        float s = two_c * sm1 - sm2;
        sm2 = sm1; sm1 = s;
        R[n] = s * inv_d;
    }

    #pragma unroll
    for (int o = 0; o < 3; o++) {
        float acc = 0.0f;
        #pragma unroll
        for (int n = 0; n < NRAD; n++)
            acc += R[n] * sW2[(o * NRAD + n) * 16 + pair];
        t[o] = acc;
    }
    g[0] = fc * vy * inv_d;
    g[1] = fc * vz * inv_d;
    g[2] = fc * vx * inv_d;
    return true;
}

__global__ __launch_bounds__(PH1_BLK) void vb_phase1(
    const float* __restrict__ vecs,
    const int*   __restrict__ centers,
    const int*   __restrict__ neighbors,
    const int*   __restrict__ species,
    const float* __restrict__ W_alch,
    const float* __restrict__ cemb,
    const float* __restrict__ Wc,
    int*         __restrict__ gcursor,   // (nbin)
    int4*        __restrict__ payload,   // (nbin, cap) 16B records
    float*       __restrict__ out,       // overflow fallback (pre-zeroed)
    int E, int nbin, int cap)
{
    __shared__ float sW2[3 * NRAD * 16];                 // 1.5 KB
    __shared__ int lcount[NBIN_MAX], lbase[NBIN_MAX], lofs[NBIN_MAX];

    build_w2(sW2, cemb, Wc, W_alch, threadIdx.x, PH1_BLK);
    for (int b = threadIdx.x; b < nbin; b += blockDim.x) { lcount[b] = 0; lofs[b] = 0; }
    __syncthreads();

    int base = blockIdx.x * (PH1_BLK * PH1_U) + threadIdx.x;
    int4 rec[PH1_U];

    #pragma unroll
    for (int u = 0; u < PH1_U; u++) {
        int e = base + u * PH1_BLK;
        rec[u].x = -1;
        if (e < E) {
            float vx = vecs[3 * e + 0];
            float vy = vecs[3 * e + 1];
            float vz = vecs[3 * e + 2];
            int c  = centers[e];
            int nb = neighbors[e];
            int pair = species[c] * 4 + species[nb];
            float g[3], t[3];
            if (edge_math(vx, vy, vz, pair, sW2, g, t)) {
                rec[u].x = c;
                rec[u].y = (int)pack2(g[0], g[1]);
                rec[u].z = (int)pack2(g[2], t[0]);
                rec[u].w = (int)pack2(t[1], t[2]);
                atomicAdd(&lcount[c >> APB_SH], 1);
            }
        }
    }
    __syncthreads();

    // one global atomic per (block, non-empty bin)
    for (int b = threadIdx.x; b < nbin; b += blockDim.x) {
        int n = lcount[b];
        lbase[b] = n ? atomicAdd(&gcursor[b], n) : 0;
    }
    __syncthreads();

    #pragma unroll
    for (int u = 0; u < PH1_U; u++) {
        int c = rec[u].x;
        if (c >= 0) {
            int bin = c >> APB_SH;
            int s = lbase[bin] + atomicAdd(&lofs[bin], 1);
            if (s < cap) {
                payload[(size_t)bin * cap + s] = rec[u];
            } else {
                // statistically ~never: direct global atomics
                float2 g01 = unpack2((unsigned)rec[u].y);
                float2 g2t = unpack2((unsigned)rec[u].z);
                float2 t12 = unpack2((unsigned)rec[u].w);
                float g[3] = { g01.x, g01.y, g2t.x };
                float t[3] = { g2t.y, t12.x, t12.y };
                float* op = out + (size_t)c * 9;
                #pragma unroll
                for (int m = 0; m < 3; m++)
                    #pragma unroll
                    for (int o = 0; o < 3; o++)
                        atomicAdd(op + m * 3 + o, g[m] * t[o]);
            }
        }
    }
}

__global__ __launch_bounds__(256) void vb_phase2(
    const int*  __restrict__ gcursor,
    const int4* __restrict__ payload,
    float*      __restrict__ partial,    // (SPLIT, out_elems)
    int out_elems, int cap)
{
    __shared__ float acc[APB * 9];       // 18 KB
    int blk = blockIdx.x;
    int b = blk >> 2;                    // bin
    int s = blk & 3;                     // split id

    for (int i = threadIdx.x; i < APB * 9; i += blockDim.x) acc[i] = 0.0f;
    __syncthreads();

    int count = min(gcursor[b], cap);
    int lo = (count * s) >> 2;
    int hi = (count * (s + 1)) >> 2;
    const int4* pb = payload + (size_t)b * cap;

    for (int i = lo + threadIdx.x; i < hi; i += blockDim.x) {
        int4 r = pb[i];
        int cl = (r.x & (APB - 1)) * 9;
        float2 g01 = unpack2((unsigned)r.y);
        float2 g2t = unpack2((unsigned)r.z);
        float2 t12 = unpack2((unsigned)r.w);
        float g0 = g01.x, g1 = g01.y, g2 = g2t.x;
        float t0 = g2t.y, t1 = t12.x, t2 = t12.y;
        atomicAdd(&acc[cl + 0], g0 * t0);
        atomicAdd(&acc[cl + 1], g0 * t1);
        atomicAdd(&acc[cl + 2], g0 * t2);
        atomicAdd(&acc[cl + 3], g1 * t0);
        atomicAdd(&acc[cl + 4], g1 * t1);
        atomicAdd(&acc[cl + 5], g1 * t2);
        atomicAdd(&acc[cl + 6], g2 * t0);
        atomicAdd(&acc[cl + 7], g2 * t1);
        atomicAdd(&acc[cl + 8], g2 * t2);
    }
    __syncthreads();

    float* pdst = partial + (size_t)s * out_elems;
    size_t gb = (size_t)b * APB * 9;
    for (int i = threadIdx.x; i < APB * 9; i += blockDim.x) {
        size_t gi = gb + i;
        if (gi < (size_t)out_elems) pdst[gi] = acc[i];
    }
}

__global__ __launch_bounds__(256) void vb_reduce(
    const float* __restrict__ partial, float* __restrict__ out, int n)
{
    int i = blockIdx.x * blockDim.x + threadIdx.x;
    if (i >= n) return;
    out[i] += partial[i] + partial[(size_t)n + i]
            + partial[2 * (size_t)n + i] + partial[3 * (size_t)n + i];
}

// Fallback: direct per-edge global atomics (correct, slow).
__global__ __launch_bounds__(256) void vb_edge_fallback(
    const float* __restrict__ vecs,
    const int*   __restrict__ centers,
    const int*   __restrict__ neighbors,
    const int*   __restrict__ species,
    const float* __restrict__ W_alch,
    const float* __restrict__ cemb,
    const float* __restrict__ Wc,
    float*       __restrict__ out,
    int E)
{
    __shared__ float sW2[3 * NRAD * 16];
    build_w2(sW2, cemb, Wc, W_alch, threadIdx.x, blockDim.x);
    __syncthreads();

    int e = blockIdx.x * blockDim.x + threadIdx.x;
    if (e >= E) return;
    float vx = vecs[3 * e + 0], vy = vecs[3 * e + 1], vz = vecs[3 * e + 2];
    int c = centers[e];
    int pair = species[c] * 4 + species[neighbors[e]];
    float g[3], t[3];
    if (!edge_math(vx, vy, vz, pair, sW2, g, t)) return;
    float* op = out + (size_t)c * 9;
    #pragma unroll
    for (int m = 0; m < 3; m++)
        #pragma unroll
        for (int o = 0; o < 3; o++)
            atomicAdd(op + m * 3 + o, g[m] * t[o]);
}

extern "C" void kernel_launch(void* const* d_in, const int* in_sizes, int n_in,
                              void* d_out, int out_size, void* d_ws, size_t ws_size,
                              hipStream_t stream) {
    const float* vecs      = (const float*)d_in[0];
    const int*   centers   = (const int*)d_in[1];
    const int*   neighbors = (const int*)d_in[2];
    const int*   species   = (const int*)d_in[3];
    const float* W_alch    = (const float*)d_in[6];
    const float* cemb      = (const float*)d_in[7];
    const float* Wc        = (const float*)d_in[8];
    float*       out       = (float*)d_out;

    int E = in_sizes[1];
    int A = in_sizes[3];
    int nbin = (A + APB - 1) >> APB_SH;

    // ws layout: [gcursor 4KB][payload nbin*cap*16B][partial SPLIT*out*4B]
    size_t out_bytes = (size_t)out_size * sizeof(float);
    long cap = 0;
    long fixed = 4096 + (long)SPLIT * out_bytes;
    if ((long)ws_size > fixed) {
        cap = ((long)ws_size - fixed) / 16 / nbin;
        cap &= ~7L;
        if (cap > 16384) cap = 16384;
    }
    long mean = (long)E / nbin + 1;

    hipMemsetAsync(d_out, 0, out_bytes, stream);

    if (nbin <= NBIN_MAX && cap >= mean + mean / 16) {
        int*   gcursor = (int*)d_ws;
        int4*  payload = (int4*)((char*)d_ws + 4096);
        float* partial = (float*)((char*)d_ws + 4096 + (size_t)nbin * cap * 16);
        hipMemsetAsync(d_ws, 0, 4096, stream);

        int g1 = (E + PH1_BLK * PH1_U - 1) / (PH1_BLK * PH1_U);
        vb_phase1<<<g1, PH1_BLK, 0, stream>>>(vecs, centers, neighbors, species,
                                              W_alch, cemb, Wc,
                                              gcursor, payload, out,
                                              E, nbin, (int)cap);
        vb_phase2<<<nbin * SPLIT, 256, 0, stream>>>(gcursor, payload, partial,
                                                    out_size, (int)cap);
        int rg = (out_size + 255) / 256;
        vb_reduce<<<rg, 256, 0, stream>>>(partial, out, out_size);
    } else {
        int grid = (E + 255) / 256;
        vb_edge_fallback<<<grid, 256, 0, stream>>>(vecs, centers, neighbors, species,
                                                   W_alch, cemb, Wc, out, E);
    }
}

// Round 5
// 145.814 us; speedup vs baseline: 5.5674x; 1.4918x over previous
//
#include <hip/hip_runtime.h>
#include <hip/hip_fp16.h>

// VectorBasis R5. Diagnosis from R3/R4: LDS f32 atomics serialize per LANE
// (~4 cyc each per CU); 14.4M of them = the 100 us phase2 floor, invariant
// under occupancy. Fix: counting sort. Phase2 sorts its records by atom in
// LDS (2 int LDS atomics/record instead of 9 f32), then accumulates each
// atom's run in REGISTERS and writes partials with plain coalesced stores.
// Phase1 uses the same LDS sort (by bin) to turn the scattered 16B payload
// writes into contiguous per-bin runs (coalesced int4 stores).

constexpr int NSP  = 4;
constexpr int NRAD = 8;
constexpr int NPS  = 4;
constexpr int DDIM = NRAD * NPS;       // 32

constexpr int APB      = 512;          // atoms per bin
constexpr int APB_SH   = 9;
constexpr int NBIN_MAX = 256;
constexpr int SPLIT    = 4;            // phase2 sub-blocks per bin
constexpr int PH1_BLK  = 512;
constexpr int PH1_U    = 4;
constexpr int PH1_REC  = PH1_BLK * PH1_U;  // 2048 records per phase1 block
constexpr int CAP2     = 3072;         // phase2 per-sub-block record capacity

__device__ __forceinline__ unsigned pack2(float a, float b) {
    union { __half2 h; unsigned u; } cv;
    cv.h = __floats2half2_rn(a, b);
    return cv.u;
}
__device__ __forceinline__ float2 unpack2(unsigned u) {
    union { unsigned u; __half2 h; } cv;
    cv.u = u;
    return __half22float2(cv.h);
}

// W2[(o*8+n)*16 + (sc*4+sn)] = sum_q cemb[sc][n*4+q]*Wc[o][n*4+q]*alch[sn][q]
__device__ __forceinline__ void build_w2(
    float* sW2, const float* cemb, const float* Wc, const float* W_alch,
    int tid, int nthreads)
{
    for (int i = tid; i < 3 * NRAD * 16; i += nthreads) {
        int p  = i & 15;
        int n  = (i >> 4) & 7;
        int o  = i >> 7;
        int sc = p >> 2, sn = p & 3;
        float w = 0.0f;
        #pragma unroll
        for (int q = 0; q < NPS; q++)
            w += cemb[sc * DDIM + n * NPS + q] * Wc[o * DDIM + n * NPS + q]
               * W_alch[sn * NPS + q];
        sW2[i] = w;
    }
}

__device__ __forceinline__ bool edge_math(
    float vx, float vy, float vz, int pair, const float* sW2,
    float g[3], float t[3])
{
    float d2    = vx * vx + vy * vy + vz * vz + 1e-12f;
    float d     = sqrtf(d2);
    float inv_d = 1.0f / d;

    const float PI = 3.14159265358979323846f;
    const float RCUT = 5.0f, INNER = 4.5f, INVW = 2.0f;
    if (d >= RCUT) return false;
    float taper = 0.5f * (cosf(PI * (d - INNER) * INVW) + 1.0f);
    float fc = (d < INNER) ? 1.0f : taper;

    float theta = (PI / RCUT) * d;
    float s1 = sinf(theta);
    float c1 = cosf(theta);
    float two_c = 2.0f * c1;
    float R[NRAD];
    R[0] = s1 * inv_d;
    float sm2 = 0.0f, sm1 = s1;
    #pragma unroll
    for (int n = 1; n < NRAD; n++) {
        float s = two_c * sm1 - sm2;
        sm2 = sm1; sm1 = s;
        R[n] = s * inv_d;
    }

    #pragma unroll
    for (int o = 0; o < 3; o++) {
        float acc = 0.0f;
        #pragma unroll
        for (int n = 0; n < NRAD; n++)
            acc += R[n] * sW2[(o * NRAD + n) * 16 + pair];
        t[o] = acc;
    }
    g[0] = fc * vy * inv_d;
    g[1] = fc * vz * inv_d;
    g[2] = fc * vx * inv_d;
    return true;
}

__device__ __forceinline__ void atomic_spill(float* out, int c,
                                             int ry, int rz, int rw)
{
    float2 g01 = unpack2((unsigned)ry);
    float2 g2t = unpack2((unsigned)rz);
    float2 t12 = unpack2((unsigned)rw);
    float g[3] = { g01.x, g01.y, g2t.x };
    float t[3] = { g2t.y, t12.x, t12.y };
    float* op = out + (size_t)c * 9;
    #pragma unroll
    for (int m = 0; m < 3; m++)
        #pragma unroll
        for (int o = 0; o < 3; o++)
            atomicAdd(op + m * 3 + o, g[m] * t[o]);
}

__global__ __launch_bounds__(PH1_BLK) void vb_phase1(
    const float* __restrict__ vecs,
    const int*   __restrict__ centers,
    const int*   __restrict__ neighbors,
    const int*   __restrict__ species,
    const float* __restrict__ W_alch,
    const float* __restrict__ cemb,
    const float* __restrict__ Wc,
    int*         __restrict__ gcursor,   // (nbin)
    int4*        __restrict__ payload,   // (nbin, cap) 16B records
    float*       __restrict__ out,       // overflow target (pre-zeroed)
    int E, int cap)
{
    __shared__ float sW2[3 * NRAD * 16];            // 1.5 KB
    __shared__ int4  srec[PH1_REC];                 // 32 KB
    __shared__ int lcount[NBIN_MAX], lscan[NBIN_MAX], lexcl[NBIN_MAX],
                   lbase[NBIN_MAX], lcur[NBIN_MAX]; // 5 KB

    int tid = threadIdx.x;
    build_w2(sW2, cemb, Wc, W_alch, tid, PH1_BLK);
    for (int i = tid; i < NBIN_MAX; i += PH1_BLK) lcount[i] = 0;
    __syncthreads();

    int4 rec[PH1_U];
    #pragma unroll
    for (int u = 0; u < PH1_U; u++) {
        int e = blockIdx.x * PH1_REC + u * PH1_BLK + tid;
        rec[u].x = -1;
        if (e < E) {
            float vx = vecs[3 * e + 0];
            float vy = vecs[3 * e + 1];
            float vz = vecs[3 * e + 2];
            int c  = centers[e];
            int pair = species[c] * 4 + species[neighbors[e]];
            float g[3], t[3];
            if (edge_math(vx, vy, vz, pair, sW2, g, t)) {
                rec[u].x = c;
                rec[u].y = (int)pack2(g[0], g[1]);
                rec[u].z = (int)pack2(g[2], t[0]);
                rec[u].w = (int)pack2(t[1], t[2]);
                atomicAdd(&lcount[c >> APB_SH], 1);
            }
        }
    }
    __syncthreads();

    // inclusive scan of lcount over NBIN_MAX entries (first 256 threads)
    if (tid < NBIN_MAX) lscan[tid] = lcount[tid];
    __syncthreads();
    for (int off = 1; off < NBIN_MAX; off <<= 1) {
        int v = 0;
        if (tid < NBIN_MAX) {
            v = lscan[tid];
            if (tid >= off) v += lscan[tid - off];
        }
        __syncthreads();
        if (tid < NBIN_MAX) lscan[tid] = v;
        __syncthreads();
    }
    if (tid < NBIN_MAX) {
        int ex = lscan[tid] - lcount[tid];
        lexcl[tid] = ex;
        lcur[tid]  = ex;
        int n = lcount[tid];
        lbase[tid] = n ? atomicAdd(&gcursor[tid], n) : 0;
    }
    __syncthreads();

    // scatter records into LDS sorted by bin
    #pragma unroll
    for (int u = 0; u < PH1_U; u++) {
        if (rec[u].x >= 0) {
            int bin = rec[u].x >> APB_SH;
            int p = atomicAdd(&lcur[bin], 1);
            srec[p] = rec[u];
        }
    }
    __syncthreads();

    // write out contiguous per-bin runs (coalesced)
    int total = lscan[NBIN_MAX - 1];
    for (int i = tid; i < total; i += PH1_BLK) {
        int4 r = srec[i];
        int bin  = r.x >> APB_SH;
        int slot = lbase[bin] + (i - lexcl[bin]);
        if (slot < cap)
            payload[(size_t)bin * cap + slot] = r;
        else
            atomic_spill(out, r.x, r.y, r.z, r.w);
    }
}

__global__ __launch_bounds__(256) void vb_phase2(
    const int*  __restrict__ gcursor,
    const int4* __restrict__ payload,
    float*      __restrict__ partial,   // (SPLIT, out_elems), fully overwritten
    float*      __restrict__ out,       // overflow target (pre-zeroed)
    int out_elems, int cap)
{
    __shared__ int4 srec2[CAP2];                    // 48 KB
    __shared__ unsigned short sidx[CAP2];           // 6 KB
    __shared__ int cnt[APB], cscan[APB], ccur[APB]; // 6 KB

    int b = blockIdx.x / SPLIT;
    int s = blockIdx.x % SPLIT;
    int tid = threadIdx.x;

    for (int i = tid; i < APB; i += 256) cnt[i] = 0;
    __syncthreads();

    int count = min(gcursor[b], cap);
    int lo = (int)(((long)count * s) / SPLIT);
    int hi = (int)(((long)count * (s + 1)) / SPLIT);
    int n  = hi - lo;
    int nc = min(n, CAP2);
    const int4* pb = payload + (size_t)b * cap + lo;

    // load + histogram (1 int LDS atomic per record)
    for (int i = tid; i < nc; i += 256) {
        int4 r = pb[i];
        srec2[i] = r;
        atomicAdd(&cnt[r.x & (APB - 1)], 1);
    }
    __syncthreads();

    // inclusive scan over APB=512 entries, 2 per thread (Hillis-Steele)
    cscan[tid] = cnt[tid];
    cscan[tid + 256] = cnt[tid + 256];
    __syncthreads();
    for (int off = 1; off < APB; off <<= 1) {
        int i0 = tid, i1 = tid + 256;
        int v0 = cscan[i0]; if (i0 >= off) v0 += cscan[i0 - off];
        int v1 = cscan[i1]; if (i1 >= off) v1 += cscan[i1 - off];
        __syncthreads();
        cscan[i0] = v0;
        cscan[i1] = v1;
        __syncthreads();
    }
    ccur[tid] = cscan[tid] - cnt[tid];
    ccur[tid + 256] = cscan[tid + 256] - cnt[tid + 256];
    __syncthreads();

    // scatter indices sorted by atom (1 int LDS atomic per record)
    for (int i = tid; i < nc; i += 256) {
        int a = srec2[i].x & (APB - 1);
        int p = atomicAdd(&ccur[a], 1);
        sidx[p] = (unsigned short)i;
    }
    __syncthreads();

    // per-atom register reduction, plain stores to partial
    for (int a = tid; a < APB; a += 256) {
        int en = cscan[a];
        int st = en - cnt[a];
        float acc[9] = {0,0,0,0,0,0,0,0,0};
        for (int j = st; j < en; j++) {
            int4 r = srec2[sidx[j]];
            float2 g01 = unpack2((unsigned)r.y);
            float2 g2t = unpack2((unsigned)r.z);
            float2 t12 = unpack2((unsigned)r.w);
            float g0 = g01.x, g1 = g01.y, g2 = g2t.x;
            float t0 = g2t.y, t1 = t12.x, t2 = t12.y;
            acc[0] += g0 * t0; acc[1] += g0 * t1; acc[2] += g0 * t2;
            acc[3] += g1 * t0; acc[4] += g1 * t1; acc[5] += g1 * t2;
            acc[6] += g2 * t0; acc[7] += g2 * t1; acc[8] += g2 * t2;
        }
        size_t gi = ((size_t)(b << APB_SH) + a) * 9;
        if (gi < (size_t)out_elems) {
            float* pd = partial + (size_t)s * out_elems + gi;
            #pragma unroll
            for (int k = 0; k < 9; k++) pd[k] = acc[k];
        }
    }

    // overflow records (slice > CAP2; statistically never)
    for (int i = CAP2 + tid; i < n; i += 256) {
        int4 r = pb[i];
        atomic_spill(out, r.x, r.y, r.z, r.w);
    }
}

__global__ __launch_bounds__(256) void vb_reduce(
    const float* __restrict__ partial, float* __restrict__ out, int n)
{
    int i = blockIdx.x * blockDim.x + threadIdx.x;
    if (i >= n) return;
    out[i] += partial[i] + partial[(size_t)n + i]
            + partial[2 * (size_t)n + i] + partial[3 * (size_t)n + i];
}

// Fallback: direct per-edge global atomics (correct, slow).
__global__ __launch_bounds__(256) void vb_edge_fallback(
    const float* __restrict__ vecs,
    const int*   __restrict__ centers,
    const int*   __restrict__ neighbors,
    const int*   __restrict__ species,
    const float* __restrict__ W_alch,
    const float* __restrict__ cemb,
    const float* __restrict__ Wc,
    float*       __restrict__ out,
    int E)
{
    __shared__ float sW2[3 * NRAD * 16];
    build_w2(sW2, cemb, Wc, W_alch, threadIdx.x, blockDim.x);
    __syncthreads();

    int e = blockIdx.x * blockDim.x + threadIdx.x;
    if (e >= E) return;
    float vx = vecs[3 * e + 0], vy = vecs[3 * e + 1], vz = vecs[3 * e + 2];
    int c = centers[e];
    int pair = species[c] * 4 + species[neighbors[e]];
    float g[3], t[3];
    if (!edge_math(vx, vy, vz, pair, sW2, g, t)) return;
    float* op = out + (size_t)c * 9;
    #pragma unroll
    for (int m = 0; m < 3; m++)
        #pragma unroll
        for (int o = 0; o < 3; o++)
            atomicAdd(op + m * 3 + o, g[m] * t[o]);
}

extern "C" void kernel_launch(void* const* d_in, const int* in_sizes, int n_in,
                              void* d_out, int out_size, void* d_ws, size_t ws_size,
                              hipStream_t stream) {
    const float* vecs      = (const float*)d_in[0];
    const int*   centers   = (const int*)d_in[1];
    const int*   neighbors = (const int*)d_in[2];
    const int*   species   = (const int*)d_in[3];
    const float* W_alch    = (const float*)d_in[6];
    const float* cemb      = (const float*)d_in[7];
    const float* Wc        = (const float*)d_in[8];
    float*       out       = (float*)d_out;

    int E = in_sizes[1];
    int A = in_sizes[3];
    int nbin = (A + APB - 1) >> APB_SH;

    // ws layout: [gcursor 4KB][payload nbin*cap*16B][partial SPLIT*out*4B]
    size_t out_bytes = (size_t)out_size * sizeof(float);
    long cap = 0;
    long fixed = 4096 + (long)SPLIT * out_bytes;
    if ((long)ws_size > fixed) {
        cap = ((long)ws_size - fixed) / 16 / nbin;
        cap &= ~7L;
        if (cap > 16384) cap = 16384;
    }
    long mean = (long)E / nbin + 1;

    hipMemsetAsync(d_out, 0, out_bytes, stream);

    if (nbin <= NBIN_MAX && cap >= mean + mean / 16) {
        int*   gcursor = (int*)d_ws;
        int4*  payload = (int4*)((char*)d_ws + 4096);
        float* partial = (float*)((char*)d_ws + 4096 + (size_t)nbin * cap * 16);
        hipMemsetAsync(d_ws, 0, 4096, stream);

        int g1 = (E + PH1_REC - 1) / PH1_REC;
        vb_phase1<<<g1, PH1_BLK, 0, stream>>>(vecs, centers, neighbors, species,
                                              W_alch, cemb, Wc,
                                              gcursor, payload, out, E, (int)cap);
        vb_phase2<<<nbin * SPLIT, 256, 0, stream>>>(gcursor, payload, partial,
                                                    out, out_size, (int)cap);
        int rg = (out_size + 255) / 256;
        vb_reduce<<<rg, 256, 0, stream>>>(partial, out, out_size);
    } else {
        int grid = (E + 255) / 256;
        vb_edge_fallback<<<grid, 256, 0, stream>>>(vecs, centers, neighbors, species,
                                                   W_alch, cemb, Wc, out, E);
    }
}